// Round 1
// baseline (288.396 us; speedup 1.0000x reference)
//
#include <hip/hip_runtime.h>

// Autoregressive LSTM log-prob, B=4096, L=256, H=32, D=2.
// Layout: lane = (batch, hidden unit). 32 lanes per batch, 8 batches per
// 256-thread block. Wh columns live in registers (128 VGPR/lane); h vector
// round-trips through a double-buffered per-group LDS slot each step.
// 2048 waves total = 2 waves/SIMD chip-wide.

#define LOG2E 1.4426950408889634f
#define LN2   0.6931471805599453f

__device__ __forceinline__ float fexp2(float x) { return __builtin_amdgcn_exp2f(x); }
__device__ __forceinline__ float flog2(float x) { return __builtin_amdgcn_logf(x); }
__device__ __forceinline__ float frcp(float x)  { return __builtin_amdgcn_rcpf(x); }

__device__ __forceinline__ float fsigmoid(float x) {
    // 1/(1+e^-x); saturates correctly at +-inf via exp2->{0,inf}, rcp(inf)=0
    return frcp(1.f + fexp2(-LOG2E * x));
}
__device__ __forceinline__ float ftanh(float x) {
    // 1 - 2/(e^{2x}+1)
    return 1.f - 2.f * frcp(fexp2(2.f * LOG2E * x) + 1.f);
}
__device__ __forceinline__ float felu(float x) {
    return x > 0.f ? x : fexp2(LOG2E * x) - 1.f;
}

constexpr int Bsz = 4096;
constexpr int Lseq = 256;
constexpr int Hd  = 32;
constexpr int BPB = 8;   // batches per 256-thread block

__global__ __launch_bounds__(256, 2) void lstm_logp_kernel(
    const int*   __restrict__ x,    // [B, L]
    const float* __restrict__ Wi,   // [2, 128]
    const float* __restrict__ Wh,   // [32, 128]
    const float* __restrict__ bh,   // [128]
    const float* __restrict__ Wo,   // [32, 2]
    const float* __restrict__ bo,   // [2]
    float*       __restrict__ out)  // [B]
{
    const int tid = threadIdx.x;
    const int k   = tid & 31;   // hidden unit
    const int lb  = tid >> 5;   // local batch 0..7
    const int b   = blockIdx.x * BPB + lb;

    // ---- preload weights into registers ----
    // wh[q*32+j] = Wh[j][q*32+k]  (gate q of unit k, contribution from h[j])
    float wh[128];
#pragma unroll
    for (int j = 0; j < 32; ++j) {
#pragma unroll
        for (int q = 0; q < 4; ++q) {
            wh[q * 32 + j] = Wh[j * 128 + q * 32 + k];
        }
    }
    float wi0[4], wi1[4], bhv[4];
#pragma unroll
    for (int q = 0; q < 4; ++q) {
        wi0[q] = Wi[0 * 128 + q * 32 + k];
        wi1[q] = Wi[1 * 128 + q * 32 + k];
        bhv[q] = bh[q * 32 + k];
    }
    const float wo0 = Wo[k * 2 + 0];
    const float wo1 = Wo[k * 2 + 1];
    const float bo0 = bo[0];
    const float bo1 = bo[1];

    // ---- LDS h buffers (double buffered; sharing is intra-32-lane-group only)
    __shared__ float hs[2][BPB][Hd];
    hs[0][lb][k] = 0.f;
    __syncthreads();

    float c = 0.f, h = 0.f, lp = 0.f;
    float wic[4] = {0.f, 0.f, 0.f, 0.f};  // Wi row for previous spin (zeros at t=0)
    const int* xb = x + b * Lseq;

    for (int t = 0; t < Lseq; ++t) {
        const int s_cur = xb[t];

        // gates = bh + Wi[s_prev] + h @ Wh
        float acc[4];
#pragma unroll
        for (int q = 0; q < 4; ++q) acc[q] = bhv[q] + wic[q];

        const float4* hv = reinterpret_cast<const float4*>(&hs[t & 1][lb][0]);
#pragma unroll
        for (int j4 = 0; j4 < 8; ++j4) {
            float4 h4 = hv[j4];
#pragma unroll
            for (int q = 0; q < 4; ++q) {
                acc[q] = fmaf(h4.x, wh[q * 32 + j4 * 4 + 0], acc[q]);
                acc[q] = fmaf(h4.y, wh[q * 32 + j4 * 4 + 1], acc[q]);
                acc[q] = fmaf(h4.z, wh[q * 32 + j4 * 4 + 2], acc[q]);
                acc[q] = fmaf(h4.w, wh[q * 32 + j4 * 4 + 3], acc[q]);
            }
        }

        // cell update (flax gate order i, f, g, o)
        const float gi = fsigmoid(acc[0]);
        const float gf = fsigmoid(acc[1]);
        const float gg = ftanh(acc[2]);
        const float go = fsigmoid(acc[3]);
        c = gf * c + gi * gg;
        h = go * ftanh(c);
        hs[(t + 1) & 1][lb][k] = h;

        // output head: S_d = sum_k h[k] * Wo[k][d], split butterfly over 32 lanes
        const float p0 = h * wo0;
        const float p1 = h * wo1;
        float aa = (k & 1) ? p1 : p0;
        float bb = (k & 1) ? p0 : p1;
        aa += __shfl_xor(bb, 1, 32);
        aa += __shfl_xor(aa, 2, 32);
        aa += __shfl_xor(aa, 4, 32);
        aa += __shfl_xor(aa, 8, 32);
        aa += __shfl_xor(aa, 16, 32);
        const float ot = __shfl_xor(aa, 1, 32);
        const float S0 = (k & 1) ? ot : aa;  // sum h*Wo[:,0]
        const float S1 = (k & 1) ? aa : ot;  // sum h*Wo[:,1]

        const float o0 = felu(S0 + bo0);
        const float o1 = felu(S1 + bo1);
        const float mx = fmaxf(o0, o1);
        const float mn = fminf(o0, o1);
        const float lse = mx + LN2 * flog2(1.f + fexp2(LOG2E * (mn - mx)));
        lp += (s_cur ? o1 : o0) - lse;

        // next step's input one-hot -> Wi row select
#pragma unroll
        for (int q = 0; q < 4; ++q) wic[q] = s_cur ? wi1[q] : wi0[q];

        __syncthreads();
    }

    if (k == 0) out[b] = 0.5f * lp;
}

extern "C" void kernel_launch(void* const* d_in, const int* in_sizes, int n_in,
                              void* d_out, int out_size, void* d_ws, size_t ws_size,
                              hipStream_t stream) {
    const int*   x  = (const int*)d_in[0];
    const float* Wi = (const float*)d_in[1];
    const float* Wh = (const float*)d_in[2];
    const float* bh = (const float*)d_in[3];
    const float* Wo = (const float*)d_in[4];
    const float* bo = (const float*)d_in[5];
    float* out = (float*)d_out;

    dim3 grid(Bsz / BPB);   // 512 blocks
    dim3 block(256);        // 8 batches/block, 32 lanes/batch
    lstm_logp_kernel<<<grid, block, 0, stream>>>(x, Wi, Wh, bh, Wo, bo, out);
}

// Round 2
// 238.764 us; speedup vs baseline: 1.2079x; 1.2079x over previous
//
#include <hip/hip_runtime.h>

// Autoregressive LSTM log-prob, B=4096, L=256, H=32, D=2.
// lane = (batch, hidden unit): 32 lanes/batch, 8 batches per 256-thread block.
// Wh held in registers as 64 float2 pairs -> v_pk_fma_f32. h round-trips
// through a per-group LDS slot (in-wave, no barrier). Output head for step
// t-1 is software-pipelined into iteration t to hide the swizzle chain.

typedef float v2f __attribute__((ext_vector_type(2)));

#define LOG2E 1.4426950408889634f
#define LN2   0.6931471805599453f

__device__ __forceinline__ float fexp2(float x) { return __builtin_amdgcn_exp2f(x); }
__device__ __forceinline__ float flog2(float x) { return __builtin_amdgcn_logf(x); }
__device__ __forceinline__ float frcp(float x)  { return __builtin_amdgcn_rcpf(x); }

__device__ __forceinline__ float fsig(float x)   { return frcp(1.f + fexp2(-LOG2E * x)); }
__device__ __forceinline__ float ftanh_(float x) { return 1.f - 2.f * frcp(fexp2(2.f * LOG2E * x) + 1.f); }
__device__ __forceinline__ float felu(float x)   { return x > 0.f ? x : fexp2(LOG2E * x) - 1.f; }

constexpr int Bsz  = 4096;
constexpr int Lseq = 256;
constexpr int BPB  = 8;   // batches per 256-thread block

// head finish for one step: pp = (h.wo0_lane, h.wo1_lane) partials, s = spin
__device__ __forceinline__ void head_finish(v2f pp, int s, int k,
                                            float bo0, float bo1, float& lp) {
    float aa = (k & 1) ? pp.y : pp.x;
    float bb = (k & 1) ? pp.x : pp.y;
    aa += __shfl_xor(bb, 1, 32);
    aa += __shfl_xor(aa, 2, 32);
    aa += __shfl_xor(aa, 4, 32);
    aa += __shfl_xor(aa, 8, 32);
    aa += __shfl_xor(aa, 16, 32);
    const float ot = __shfl_xor(aa, 1, 32);
    const float S0 = (k & 1) ? ot : aa;
    const float S1 = (k & 1) ? aa : ot;
    const float o0 = felu(S0 + bo0);
    const float o1 = felu(S1 + bo1);
    const float mx = fmaxf(o0, o1);
    const float mn = fminf(o0, o1);
    const float lse = mx + LN2 * flog2(1.f + fexp2(LOG2E * (mn - mx)));
    lp += (s ? o1 : o0) - lse;
}

__global__ __launch_bounds__(256, 2) void lstm_logp_kernel(
    const int*   __restrict__ x,    // [B, L]
    const float* __restrict__ Wi,   // [2, 128]
    const float* __restrict__ Wh,   // [32, 128]
    const float* __restrict__ bh,   // [128]
    const float* __restrict__ Wo,   // [32, 2]
    const float* __restrict__ bo,   // [2]
    float*       __restrict__ out)  // [B]
{
    const int tid = threadIdx.x;
    const int k   = tid & 31;   // hidden unit
    const int lb  = tid >> 5;   // local batch 0..7
    const int b   = blockIdx.x * BPB + lb;

    // ---- weights into registers: whp[q*16 + j2] = (Wh[2j2][q32+k], Wh[2j2+1][q32+k])
    v2f whp[64];
#pragma unroll
    for (int j2 = 0; j2 < 16; ++j2) {
#pragma unroll
        for (int q = 0; q < 4; ++q) {
            whp[q * 16 + j2] = v2f{ Wh[(2 * j2) * 128 + q * 32 + k],
                                    Wh[(2 * j2 + 1) * 128 + q * 32 + k] };
        }
    }
    // folded bias + input-row: gates start = bh + Wi[s_prev]
    float bw0[4], bw1[4];
#pragma unroll
    for (int q = 0; q < 4; ++q) {
        const float bq = bh[q * 32 + k];
        bw0[q] = bq + Wi[0 * 128 + q * 32 + k];
        bw1[q] = bq + Wi[1 * 128 + q * 32 + k];
    }
    const float wo0 = Wo[k * 2 + 0];
    const float wo1 = Wo[k * 2 + 1];
    const float bo0 = bo[0];
    const float bo1 = bo[1];

    __shared__ float hs[2][BPB][32];
    const int* xb = x + b * Lseq;

    // ---- step 0 peel: input = 0, h = 0 -> gates = bh
    float c, h, lp = 0.f;
    {
        const float g0 = bh[0 * 32 + k];
        const float g2 = bh[2 * 32 + k];
        const float g3 = bh[3 * 32 + k];
        c = fsig(g0) * ftanh_(g2);          // c0 = 0, so f-gate term vanishes
        h = fsig(g3) * ftanh_(c);
    }
    hs[0][lb][k] = h;
    v2f pp = v2f{ h * wo0, h * wo1 };
    int s_prev = xb[0];   // spin for head(step 0) and input one-hot for step 1

    for (int t = 1; t < Lseq; ++t) {
        const float4* hv = reinterpret_cast<const float4*>(&hs[(t + 1) & 1][lb][0]);

        // gate accumulators seeded with bh + Wi[s_prev]
        v2f acc[4];
#pragma unroll
        for (int q = 0; q < 4; ++q)
            acc[q] = v2f{ s_prev ? bw1[q] : bw0[q], 0.f };

        // head for step t-1 — independent of the FMA block below; the
        // scheduler interleaves the swizzle chain under the pk-FMA stream.
        head_finish(pp, s_prev, k, bo0, bo1, lp);

        // gates += h_{t-1} @ Wh  (64 packed fp32 FMAs)
#pragma unroll
        for (int j4 = 0; j4 < 8; ++j4) {
            const float4 h4 = hv[j4];
            const v2f hlo = v2f{ h4.x, h4.y };
            const v2f hhi = v2f{ h4.z, h4.w };
#pragma unroll
            for (int q = 0; q < 4; ++q) {
                acc[q] = __builtin_elementwise_fma(hlo, whp[q * 16 + 2 * j4],     acc[q]);
                acc[q] = __builtin_elementwise_fma(hhi, whp[q * 16 + 2 * j4 + 1], acc[q]);
            }
        }
        const float gi = fsig(acc[0].x + acc[0].y);
        const float gf = fsig(acc[1].x + acc[1].y);
        const float gg = ftanh_(acc[2].x + acc[2].y);
        const float go = fsig(acc[3].x + acc[3].y);
        c = gf * c + gi * gg;
        h = go * ftanh_(c);
        hs[t & 1][lb][k] = h;

        pp = v2f{ h * wo0, h * wo1 };
        s_prev = xb[t];
    }

    // final head for step L-1
    head_finish(pp, s_prev, k, bo0, bo1, lp);

    if (k == 0) out[b] = 0.5f * lp;
}

extern "C" void kernel_launch(void* const* d_in, const int* in_sizes, int n_in,
                              void* d_out, int out_size, void* d_ws, size_t ws_size,
                              hipStream_t stream) {
    const int*   x  = (const int*)d_in[0];
    const float* Wi = (const float*)d_in[1];
    const float* Wh = (const float*)d_in[2];
    const float* bh = (const float*)d_in[3];
    const float* Wo = (const float*)d_in[4];
    const float* bo = (const float*)d_in[5];
    float* out = (float*)d_out;

    dim3 grid(Bsz / BPB);   // 512 blocks
    dim3 block(256);        // 8 batches/block, 32 lanes/batch
    lstm_logp_kernel<<<grid, block, 0, stream>>>(x, Wi, Wh, bh, Wo, bo, out);
}